// Round 1
// baseline (440.315 us; speedup 1.0000x reference)
//
#include <hip/hip_runtime.h>
#include <hip/hip_bf16.h>
#include <stdint.h>

typedef __hip_bfloat16 bf16;
typedef __attribute__((ext_vector_type(8))) short short8;
typedef __attribute__((ext_vector_type(4))) float float4v;

static constexpr int nB = 2, nS = 2048, nD = 1024, nH = 16, nHD = 64;
static constexpr int nBS = nB * nS;   // 4096

#define AS_GLOBAL __attribute__((address_space(1)))
#define AS_LDS    __attribute__((address_space(3)))

union Frag16B { short8 v; uint4 u4; uint2 u2[2]; };

__device__ __forceinline__ void gload_lds16(const void* g, void* l) {
  __builtin_amdgcn_global_load_lds((AS_GLOBAL uint32_t*)(g), (AS_LDS uint32_t*)(l), 16, 0, 0);
}

// ---------------------------------------------------------------- cast fp32 -> bf16
__global__ __launch_bounds__(256) void cast_f32_bf16_kernel(const float* __restrict__ in,
                                                            bf16* __restrict__ out, int n4) {
  int i = blockIdx.x * 256 + threadIdx.x;
  if (i >= n4) return;
  float4 v = ((const float4*)in)[i];
  union { bf16 b[4]; uint2 u; } tmp;
  tmp.b[0] = __float2bfloat16(v.x);
  tmp.b[1] = __float2bfloat16(v.y);
  tmp.b[2] = __float2bfloat16(v.z);
  tmp.b[3] = __float2bfloat16(v.w);
  ((uint2*)out)[i] = tmp.u;
}

// ---------------------------------------------------------------- W (fp32 [K][N]) -> W^T (bf16 [N][K])
__global__ __launch_bounds__(256) void transpose_w_kernel(
    const float* __restrict__ W0, const float* __restrict__ W1,
    const float* __restrict__ W2, const float* __restrict__ W3,
    bf16* __restrict__ T0, bf16* __restrict__ T1, bf16* __restrict__ T2, bf16* __restrict__ T3) {
  __shared__ float tile[64][65];
  int z = blockIdx.z;
  const float* W = z == 0 ? W0 : z == 1 ? W1 : z == 2 ? W2 : W3;
  bf16* T = z == 0 ? T0 : z == 1 ? T1 : z == 2 ? T2 : T3;
  int tk = blockIdx.x * 64, tn = blockIdx.y * 64;
  int t = threadIdx.x;
  int c = t & 63, r0 = t >> 6;
#pragma unroll
  for (int i = 0; i < 16; ++i) {
    int r = i * 4 + r0;
    tile[r][c] = W[(size_t)(tk + r) * nD + tn + c];
  }
  __syncthreads();
#pragma unroll
  for (int i = 0; i < 16; ++i) {
    int r = i * 4 + r0;
    T[(size_t)(tn + r) * nD + tk + c] = __float2bfloat16(tile[c][r]);
  }
}

// ---------------------------------------------------------------- v_ws fp32 [B][S][D] -> vt bf16 [B][H][HD][S]
__global__ __launch_bounds__(256) void transpose_v_kernel(const float* __restrict__ v_ws,
                                                          bf16* __restrict__ vt_h) {
  __shared__ float tile[64][65];
  int b = blockIdx.z;
  int ts = blockIdx.x * 64;   // s tile base
  int h = blockIdx.y;         // head (64-wide d tile)
  int t = threadIdx.x;
  int c = t & 63, r0 = t >> 6;
#pragma unroll
  for (int i = 0; i < 16; ++i) {
    int r = i * 4 + r0;       // s-local
    tile[r][c] = v_ws[((size_t)(b * nS + ts + r)) * nD + h * 64 + c];
  }
  __syncthreads();
#pragma unroll
  for (int i = 0; i < 16; ++i) {
    int r = i * 4 + r0;       // d-local
    vt_h[((size_t)(b * nH + h) * 64 + r) * nS + ts + c] = __float2bfloat16(tile[c][r]);
  }
}

// ---------------------------------------------------------------- bf16 GEMM: C[M][N] = A[M][K] * Bt[N][K]^T  (fp32 out)
// m97 structure: 128x128 tile, BK=32, 4 waves, global_load_lds width 16.
__global__ __launch_bounds__(256) void gemm_bf16_kernel(
    const bf16* __restrict__ A0, const bf16* __restrict__ A1, const bf16* __restrict__ A2,
    const bf16* __restrict__ Bt0, const bf16* __restrict__ Bt1, const bf16* __restrict__ Bt2,
    float* __restrict__ C0, float* __restrict__ C1, float* __restrict__ C2,
    int M, int N, int K) {
  const bf16* A  = blockIdx.z == 0 ? A0 : (blockIdx.z == 1 ? A1 : A2);
  const bf16* Bt = blockIdx.z == 0 ? Bt0 : (blockIdx.z == 1 ? Bt1 : Bt2);
  float* C = blockIdx.z == 0 ? C0 : (blockIdx.z == 1 ? C1 : C2);

  __shared__ bf16 As[128 * 32];
  __shared__ bf16 Bs[128 * 32];

  const int t = threadIdx.x;
  const int lane = t & 63;
  const int wid = t >> 6;
  const int quad = lane >> 4;
  const int l16 = lane & 15;
  const int wm = wid >> 1;   // 0..1
  const int wn = wid & 1;    // 0..1

  const int m0 = blockIdx.y * 128;
  const int n0 = blockIdx.x * 128;

  float4v acc[4][4] = {};

  for (int kt = 0; kt < K; kt += 32) {
    __syncthreads();
#pragma unroll
    for (int p = 0; p < 2; ++p) {
      int cch = p * 256 + wid * 64 + lane;
      int row = cch >> 2, cc = cch & 3;
      gload_lds16(A + (size_t)(m0 + row) * K + kt + cc * 8, As + (size_t)(p * 256 + wid * 64) * 8);
      gload_lds16(Bt + (size_t)(n0 + row) * K + kt + cc * 8, Bs + (size_t)(p * 256 + wid * 64) * 8);
    }
    __syncthreads();

    Frag16B a[4], b[4];
#pragma unroll
    for (int mi = 0; mi < 4; ++mi)
      a[mi].u4 = *(const uint4*)&As[(wm * 64 + mi * 16 + l16) * 32 + quad * 8];
#pragma unroll
    for (int ni = 0; ni < 4; ++ni)
      b[ni].u4 = *(const uint4*)&Bs[(wn * 64 + ni * 16 + l16) * 32 + quad * 8];
#pragma unroll
    for (int mi = 0; mi < 4; ++mi)
#pragma unroll
      for (int ni = 0; ni < 4; ++ni)
        acc[mi][ni] = __builtin_amdgcn_mfma_f32_16x16x32_bf16(a[mi].v, b[ni].v, acc[mi][ni], 0, 0, 0);
  }

#pragma unroll
  for (int mi = 0; mi < 4; ++mi)
#pragma unroll
    for (int ni = 0; ni < 4; ++ni)
#pragma unroll
      for (int r = 0; r < 4; ++r) {
        int row = m0 + wm * 64 + mi * 16 + quad * 4 + r;
        int col = n0 + wn * 64 + ni * 16 + l16;
        C[(size_t)row * N + col] = acc[mi][ni][r];
      }
}

// ---------------------------------------------------------------- RoPE + RMSNorm on q,k: fp32 in -> bf16 out
__global__ __launch_bounds__(256) void rope_rms_kernel(const float* __restrict__ q_ws,
                                                       const float* __restrict__ k_ws,
                                                       bf16* __restrict__ q_h, bf16* __restrict__ k_h) {
  int t = threadIdx.x;
  int lane32 = t & 31;
  int gr = blockIdx.x * 8 + (t >> 5);
  const int NR = nB * nS * nH;  // 65536 rows per tensor
  int tensor = gr >= NR ? 1 : 0;
  int r = tensor ? gr - NR : gr;
  int b = r / (nS * nH);
  int rem = r - b * (nS * nH);
  int s = rem / nH;
  int h = rem - s * nH;
  size_t off = ((size_t)(b * nS + s)) * nD + h * 64;
  const float* src = (tensor ? k_ws : q_ws) + off;
  bf16* dst = (tensor ? k_h : q_h) + off;
  float x1 = src[lane32], x2 = src[lane32 + 32];
  float inv_freq = powf(100000.0f, -(float)(2 * lane32) / 64.0f);
  float gamma = (float)s * inv_freq;
  float cg = __bfloat162float(__float2bfloat16(cosf(gamma)));
  float sg = __bfloat162float(__float2bfloat16(sinf(gamma)));
  float y1 = x1 * cg + x2 * sg;
  float y2 = x2 * cg - x1 * sg;
  float ss2 = y1 * y1 + y2 * y2;
#pragma unroll
  for (int m = 1; m < 32; m <<= 1) ss2 += __shfl_xor(ss2, m, 32);
  float inv_rms = 1.0f / sqrtf(ss2 * (1.0f / 64.0f) + 1e-9f);
  dst[lane32] = __float2bfloat16(y1 * inv_rms);
  dst[lane32 + 32] = __float2bfloat16(y2 * inv_rms);
}

// ---------------------------------------------------------------- flash attention (causal), bf16 MFMA
// block = (qt, b*H + h); 64 q-rows per block, 4 waves x 16 rows; K/V tiles of 64.
static constexpr int KSTR = 68;  // 64 + 4 pad (keeps 8B align, <=4-way LDS conflicts)

__global__ __launch_bounds__(256) void attn_kernel(const bf16* __restrict__ q_h,
                                                   const bf16* __restrict__ k_h,
                                                   const bf16* __restrict__ vt_h,
                                                   bf16* __restrict__ vals) {
  __shared__ bf16 Kl[64 * KSTR];
  __shared__ bf16 Vl[64 * KSTR];        // transposed: [d][key]
  __shared__ bf16 Pl[4 * 16 * KSTR];    // per-wave P tiles

  int t = threadIdx.x;
  int lane = t & 63, wid = t >> 6, quad = lane >> 4, l16 = lane & 15;
  int qt = gridDim.x - 1 - blockIdx.x;  // long blocks first
  int bh = blockIdx.y;
  int b = bh >> 4, h = bh & 15;

  // Q fragments (A-layout: m = l16, k = quad*8 + j, 2 k-steps)
  Frag16B qf[2];
  {
    int qrow = qt * 64 + wid * 16 + l16;
    const bf16* qp = q_h + ((size_t)(b * nS + qrow)) * nD + h * 64;
    qf[0].u4 = *(const uint4*)(qp + quad * 8);
    qf[1].u4 = *(const uint4*)(qp + 32 + quad * 8);
  }

  float4v o_acc[4] = {};
  float m_i[4], l_i[4];
#pragma unroll
  for (int r = 0; r < 4; ++r) { m_i[r] = -1e30f; l_i[r] = 0.f; }

  const bf16* Kbase = k_h + ((size_t)b * nS) * nD + h * 64;
  const bf16* Vbase = vt_h + ((size_t)(b * nH + h)) * nHD * nS;
  bf16* Pw = Pl + wid * 16 * KSTR;

  for (int kt = 0; kt <= qt; ++kt) {
    __syncthreads();
    // stage K tile [key][d] and V^T tile [d][key]
#pragma unroll
    for (int p = 0; p < 2; ++p) {
      int c = p * 256 + t;
      int row = c >> 3, cc = c & 7;
      uint4 kv = *(const uint4*)(Kbase + ((size_t)(kt * 64 + row)) * nD + cc * 8);
      uint2 klo; klo.x = kv.x; klo.y = kv.y;
      uint2 khi; khi.x = kv.z; khi.y = kv.w;
      *(uint2*)&Kl[row * KSTR + cc * 8] = klo;
      *(uint2*)&Kl[row * KSTR + cc * 8 + 4] = khi;
      uint4 vv = *(const uint4*)(Vbase + (size_t)row * nS + kt * 64 + cc * 8);
      uint2 vlo; vlo.x = vv.x; vlo.y = vv.y;
      uint2 vhi; vhi.x = vv.z; vhi.y = vv.w;
      *(uint2*)&Vl[row * KSTR + cc * 8] = vlo;
      *(uint2*)&Vl[row * KSTR + cc * 8 + 4] = vhi;
    }
    __syncthreads();

    // QK^T: S[m=qrow][n=key]
    float4v s_acc[4] = {};
#pragma unroll
    for (int ni = 0; ni < 4; ++ni) {
      Frag16B b0, b1;
      const bf16* kp = &Kl[(ni * 16 + l16) * KSTR + quad * 8];
      b0.u2[0] = *(const uint2*)(kp);
      b0.u2[1] = *(const uint2*)(kp + 4);
      b1.u2[0] = *(const uint2*)(kp + 32);
      b1.u2[1] = *(const uint2*)(kp + 36);
      s_acc[ni] = __builtin_amdgcn_mfma_f32_16x16x32_bf16(qf[0].v, b0.v, s_acc[ni], 0, 0, 0);
      s_acc[ni] = __builtin_amdgcn_mfma_f32_16x16x32_bf16(qf[1].v, b1.v, s_acc[ni], 0, 0, 0);
    }

    // online softmax
    int qrow0 = qt * 64 + wid * 16 + quad * 4;
    bool diag = (kt == qt);
    float sv[4][4];
    float tmax[4] = {-1e30f, -1e30f, -1e30f, -1e30f};
#pragma unroll
    for (int ni = 0; ni < 4; ++ni) {
      int key = kt * 64 + ni * 16 + l16;
#pragma unroll
      for (int r = 0; r < 4; ++r) {
        float v = s_acc[ni][r] * 0.125f;
        if (diag && key > qrow0 + r) v = -1e9f;
        sv[ni][r] = v;
        tmax[r] = fmaxf(tmax[r], v);
      }
    }
#pragma unroll
    for (int m = 1; m <= 8; m <<= 1)
#pragma unroll
      for (int r = 0; r < 4; ++r)
        tmax[r] = fmaxf(tmax[r], __shfl_xor(tmax[r], m, 64));

    float rs[4];
#pragma unroll
    for (int r = 0; r < 4; ++r) {
      float mn = fmaxf(m_i[r], tmax[r]);
      float alpha = expf(m_i[r] - mn);
      m_i[r] = mn;
      l_i[r] *= alpha;
#pragma unroll
      for (int ni = 0; ni < 4; ++ni) o_acc[ni][r] *= alpha;
      rs[r] = 0.f;
    }
#pragma unroll
    for (int ni = 0; ni < 4; ++ni)
#pragma unroll
      for (int r = 0; r < 4; ++r) {
        float p = expf(sv[ni][r] - m_i[r]);
        rs[r] += p;
        Pw[(quad * 4 + r) * KSTR + ni * 16 + l16] = __float2bfloat16(p);
      }
#pragma unroll
    for (int m = 1; m <= 8; m <<= 1)
#pragma unroll
      for (int r = 0; r < 4; ++r)
        rs[r] += __shfl_xor(rs[r], m, 64);
#pragma unroll
    for (int r = 0; r < 4; ++r) l_i[r] += rs[r];

    asm volatile("s_waitcnt lgkmcnt(0)" ::: "memory");  // P writes visible to own wave's reads

    // PV: O[m=qrow][n=d] += P[m][key] * V[key][d]
    Frag16B pa[2];
    const bf16* pp = &Pw[l16 * KSTR];
    pa[0].u2[0] = *(const uint2*)(pp + quad * 8);
    pa[0].u2[1] = *(const uint2*)(pp + quad * 8 + 4);
    pa[1].u2[0] = *(const uint2*)(pp + 32 + quad * 8);
    pa[1].u2[1] = *(const uint2*)(pp + 32 + quad * 8 + 4);
#pragma unroll
    for (int ni = 0; ni < 4; ++ni) {
      Frag16B vb0, vb1;
      const bf16* vp = &Vl[(ni * 16 + l16) * KSTR + quad * 8];
      vb0.u2[0] = *(const uint2*)(vp);
      vb0.u2[1] = *(const uint2*)(vp + 4);
      vb1.u2[0] = *(const uint2*)(vp + 32);
      vb1.u2[1] = *(const uint2*)(vp + 36);
      o_acc[ni] = __builtin_amdgcn_mfma_f32_16x16x32_bf16(pa[0].v, vb0.v, o_acc[ni], 0, 0, 0);
      o_acc[ni] = __builtin_amdgcn_mfma_f32_16x16x32_bf16(pa[1].v, vb1.v, o_acc[ni], 0, 0, 0);
    }
  }

  // epilogue: O /= l, write bf16 vals [B][S][D]
  int qrow0 = qt * 64 + wid * 16 + quad * 4;
#pragma unroll
  for (int ni = 0; ni < 4; ++ni)
#pragma unroll
    for (int r = 0; r < 4; ++r) {
      float o = o_acc[ni][r] / l_i[r];
      vals[((size_t)(b * nS + qrow0 + r)) * nD + h * 64 + ni * 16 + l16] = __float2bfloat16(o);
    }
}

// ---------------------------------------------------------------- launch
extern "C" void kernel_launch(void* const* d_in, const int* in_sizes, int n_in,
                              void* d_out, int out_size, void* d_ws, size_t ws_size,
                              hipStream_t stream) {
  const float* Qin = (const float*)d_in[0];
  const float* Kin = (const float*)d_in[1];
  const float* Vin = (const float*)d_in[2];
  // d_in[3] = causal mask (structure known, ignored)
  const float* Wq = (const float*)d_in[4];
  const float* Wk = (const float*)d_in[5];
  const float* Wv = (const float*)d_in[6];
  const float* Wo = (const float*)d_in[7];
  float* out = (float*)d_out;

  char* ws = (char*)d_ws;
  const size_t MB = 1u << 20;
  // phase-1 buffers, later reused (dead by the time the alias is written)
  bf16* Qbf = (bf16*)(ws + 0 * MB);    // -> q_h after rope
  bf16* Kbf = (bf16*)(ws + 8 * MB);    // -> k_h after rope
  bf16* Vbf = (bf16*)(ws + 16 * MB);   // -> vt_h after transpose_v
  bf16* WqT = (bf16*)(ws + 24 * MB);
  bf16* WkT = (bf16*)(ws + 26 * MB);
  bf16* WvT = (bf16*)(ws + 28 * MB);
  bf16* WoT = (bf16*)(ws + 30 * MB);
  float* q_ws = (float*)(ws + 32 * MB);
  float* k_ws = (float*)(ws + 48 * MB);
  float* v_ws = (float*)(ws + 64 * MB);
  bf16* q_h = (bf16*)(ws + 0 * MB);
  bf16* k_h = (bf16*)(ws + 8 * MB);
  bf16* vt_h = (bf16*)(ws + 16 * MB);
  bf16* vals = (bf16*)(ws + 80 * MB);

  int n4 = (nBS * nD) / 4;  // 1048576
  cast_f32_bf16_kernel<<<n4 / 256, 256, 0, stream>>>(Qin, Qbf, n4);
  cast_f32_bf16_kernel<<<n4 / 256, 256, 0, stream>>>(Kin, Kbf, n4);
  cast_f32_bf16_kernel<<<n4 / 256, 256, 0, stream>>>(Vin, Vbf, n4);

  transpose_w_kernel<<<dim3(16, 16, 4), 256, 0, stream>>>(Wq, Wk, Wv, Wo, WqT, WkT, WvT, WoT);

  gemm_bf16_kernel<<<dim3(8, 32, 3), 256, 0, stream>>>(Qbf, Kbf, Vbf, WqT, WkT, WvT,
                                                       q_ws, k_ws, v_ws, nBS, nD, nD);

  rope_rms_kernel<<<(2 * nB * nS * nH) / 8, 256, 0, stream>>>(q_ws, k_ws, q_h, k_h);

  transpose_v_kernel<<<dim3(nS / 64, nH, nB), 256, 0, stream>>>(v_ws, vt_h);

  attn_kernel<<<dim3(nS / 64, nB * nH), 256, 0, stream>>>(q_h, k_h, vt_h, vals);

  gemm_bf16_kernel<<<dim3(8, 32, 1), 256, 0, stream>>>(vals, vals, vals, WoT, WoT, WoT,
                                                       out, out, out, nBS, nD, nD);
}

// Round 2
// 243.419 us; speedup vs baseline: 1.8089x; 1.8089x over previous
//
#include <hip/hip_runtime.h>
#include <hip/hip_bf16.h>
#include <stdint.h>

typedef __hip_bfloat16 bf16;
typedef __attribute__((ext_vector_type(8))) short short8;
typedef __attribute__((ext_vector_type(4))) float float4v;

static constexpr int nB = 2, nS = 2048, nD = 1024, nH = 16, nHD = 64;
static constexpr int nBS = nB * nS;   // 4096

#define AS_GLOBAL __attribute__((address_space(1)))
#define AS_LDS    __attribute__((address_space(3)))

union Frag16B { short8 v; uint4 u4; uint2 u2[2]; };

__device__ __forceinline__ void gload_lds16(const void* g, void* l) {
  __builtin_amdgcn_global_load_lds((AS_GLOBAL uint32_t*)(g), (AS_LDS uint32_t*)(l), 16, 0, 0);
}

__device__ __forceinline__ float fast_exp2(float x) {
#if __has_builtin(__builtin_amdgcn_exp2f)
  return __builtin_amdgcn_exp2f(x);
#else
  float r; asm volatile("v_exp_f32 %0, %1" : "=v"(r) : "v"(x)); return r;
#endif
}

// raw barrier: drain LDS ops but NOT vmem (prefetch loads stay in flight)
__device__ __forceinline__ void lds_barrier() {
  asm volatile("s_waitcnt lgkmcnt(0)\ns_barrier" ::: "memory");
}

// ---------------------------------------------------------------- prep: cast QKV->bf16, W->W^T bf16, rope tables
__global__ __launch_bounds__(256) void prep_kernel(
    const float* __restrict__ Qin, const float* __restrict__ Kin, const float* __restrict__ Vin,
    const float* __restrict__ Wq, const float* __restrict__ Wk,
    const float* __restrict__ Wv, const float* __restrict__ Wo,
    bf16* __restrict__ Qbf, bf16* __restrict__ Kbf, bf16* __restrict__ Vbf,
    bf16* __restrict__ WqT, bf16* __restrict__ WkT, bf16* __restrict__ WvT, bf16* __restrict__ WoT,
    bf16* __restrict__ cos_t, bf16* __restrict__ sin_t) {
  __shared__ float tile[64][65];
  int bx = blockIdx.x, t = threadIdx.x;
  if (bx < 3072) {
    int tz = bx >> 10, blk = bx & 1023;
    const float* src = tz == 0 ? Qin : tz == 1 ? Kin : Vin;
    bf16* dst = tz == 0 ? Qbf : tz == 1 ? Kbf : Vbf;
#pragma unroll
    for (int i = 0; i < 4; ++i) {
      int idx = blk * 1024 + i * 256 + t;  // float4 index
      float4 v = ((const float4*)src)[idx];
      union { bf16 b[4]; uint2 u; } tmp;
      tmp.b[0] = __float2bfloat16(v.x);
      tmp.b[1] = __float2bfloat16(v.y);
      tmp.b[2] = __float2bfloat16(v.z);
      tmp.b[3] = __float2bfloat16(v.w);
      ((uint2*)dst)[idx] = tmp.u;
    }
  } else if (bx < 4096) {
    int idx = bx - 3072;
    int z = idx >> 8;
    const float* W = z == 0 ? Wq : z == 1 ? Wk : z == 2 ? Wv : Wo;
    bf16* T = z == 0 ? WqT : z == 1 ? WkT : z == 2 ? WvT : WoT;
    int tk = (idx & 15) * 64, tn = ((idx >> 4) & 15) * 64;
    int c = t & 63, r0 = t >> 6;
#pragma unroll
    for (int i = 0; i < 16; ++i) {
      int r = i * 4 + r0;
      tile[r][c] = W[(size_t)(tk + r) * nD + tn + c];
    }
    __syncthreads();
#pragma unroll
    for (int i = 0; i < 16; ++i) {
      int r = i * 4 + r0;
      T[(size_t)(tn + r) * nD + tk + c] = __float2bfloat16(tile[c][r]);
    }
  } else {
    int base = (bx - 4096) * 1024 + t * 4;
#pragma unroll
    for (int i = 0; i < 4; ++i) {
      int e = base + i;
      int s = e >> 5, j = e & 31;
      float inv_freq = powf(100000.0f, -(float)(2 * j) / 64.0f);
      float g = (float)s * inv_freq;
      cos_t[e] = __float2bfloat16(cosf(g));
      sin_t[e] = __float2bfloat16(sinf(g));
    }
  }
}

// ---------------------------------------------------------------- fused projection GEMM (q/k: +rope+rms; v: transposed write)
__global__ __launch_bounds__(256) void gemm_qkv_kernel(
    const bf16* __restrict__ A0, const bf16* __restrict__ A1, const bf16* __restrict__ A2,
    const bf16* __restrict__ Bt0, const bf16* __restrict__ Bt1, const bf16* __restrict__ Bt2,
    bf16* __restrict__ q_h, bf16* __restrict__ k_h, bf16* __restrict__ vt_h,
    const bf16* __restrict__ cos_t, const bf16* __restrict__ sin_t) {
  const int z = blockIdx.z;
  const bf16* A  = z == 0 ? A0 : (z == 1 ? A1 : A2);
  const bf16* Bt = z == 0 ? Bt0 : (z == 1 ? Bt1 : Bt2);

  __shared__ bf16 As[128 * 32];
  __shared__ bf16 Bs[128 * 32];

  const int t = threadIdx.x;
  const int lane = t & 63;
  const int wid = t >> 6;
  const int quad = lane >> 4;
  const int l16 = lane & 15;
  const int wm = wid >> 1;
  const int wn = wid & 1;
  const int m0 = blockIdx.y * 128;
  const int n0 = blockIdx.x * 128;
  const int K = nD;

  float4v acc[4][4] = {};

  for (int kt = 0; kt < K; kt += 32) {
    __syncthreads();
#pragma unroll
    for (int p = 0; p < 2; ++p) {
      int cch = p * 256 + wid * 64 + lane;
      int row = cch >> 2, cc = cch & 3;
      gload_lds16(A + (size_t)(m0 + row) * K + kt + cc * 8, As + (size_t)(p * 256 + wid * 64) * 8);
      gload_lds16(Bt + (size_t)(n0 + row) * K + kt + cc * 8, Bs + (size_t)(p * 256 + wid * 64) * 8);
    }
    __syncthreads();

    Frag16B a[4], b[4];
#pragma unroll
    for (int mi = 0; mi < 4; ++mi)
      a[mi].u4 = *(const uint4*)&As[(wm * 64 + mi * 16 + l16) * 32 + quad * 8];
#pragma unroll
    for (int ni = 0; ni < 4; ++ni)
      b[ni].u4 = *(const uint4*)&Bs[(wn * 64 + ni * 16 + l16) * 32 + quad * 8];
#pragma unroll
    for (int mi = 0; mi < 4; ++mi)
#pragma unroll
      for (int ni = 0; ni < 4; ++ni)
        acc[mi][ni] = __builtin_amdgcn_mfma_f32_16x16x32_bf16(a[mi].v, b[ni].v, acc[mi][ni], 0, 0, 0);
  }

  const int col0 = n0 + wn * 64;   // multiple of 64 -> one head per wave
  if (z <= 1) {
    bf16* dst = z ? k_h : q_h;
#pragma unroll
    for (int mi = 0; mi < 4; ++mi)
#pragma unroll
      for (int r = 0; r < 4; ++r) {
        int row = m0 + wm * 64 + mi * 16 + quad * 4 + r;
        int s = row & (nS - 1);
        float x0 = acc[mi][0][r], x1 = acc[mi][1][r], x2 = acc[mi][2][r], x3 = acc[mi][3][r];
        float y[4];
#pragma unroll
        for (int p = 0; p < 2; ++p) {
          int d = p * 16 + l16;
          float c = __bfloat162float(cos_t[s * 32 + d]);
          float sn = __bfloat162float(sin_t[s * 32 + d]);
          float xa = p ? x1 : x0, xb = p ? x3 : x2;
          y[p] = xa * c + xb * sn;
          y[p + 2] = xb * c - xa * sn;
        }
        float ss = y[0] * y[0] + y[1] * y[1] + y[2] * y[2] + y[3] * y[3];
#pragma unroll
        for (int m = 1; m <= 8; m <<= 1) ss += __shfl_xor(ss, m, 64);
        float inv = 1.0f / sqrtf(ss * (1.0f / 64.0f) + 1e-9f);
#pragma unroll
        for (int ni = 0; ni < 4; ++ni)
          dst[(size_t)row * nD + col0 + ni * 16 + l16] = __float2bfloat16(y[ni] * inv);
      }
  } else {
    // V: write transposed -> vt_h [b][h][d][s]
#pragma unroll
    for (int mi = 0; mi < 4; ++mi)
#pragma unroll
      for (int r = 0; r < 4; ++r) {
        int row = m0 + wm * 64 + mi * 16 + quad * 4 + r;
        int b = row >> 11, s = row & (nS - 1);
#pragma unroll
        for (int ni = 0; ni < 4; ++ni) {
          int col = col0 + ni * 16 + l16;
          int h = col >> 6, d = col & 63;
          vt_h[((size_t)((b * nH + h) * 64 + d)) * nS + s] = __float2bfloat16(acc[mi][ni][r]);
        }
      }
  }
}

// ---------------------------------------------------------------- output GEMM (fp32 out)
__global__ __launch_bounds__(256) void gemm_out_kernel(
    const bf16* __restrict__ A, const bf16* __restrict__ Bt, float* __restrict__ C) {
  __shared__ bf16 As[128 * 32];
  __shared__ bf16 Bs[128 * 32];
  const int t = threadIdx.x;
  const int lane = t & 63;
  const int wid = t >> 6;
  const int quad = lane >> 4;
  const int l16 = lane & 15;
  const int wm = wid >> 1;
  const int wn = wid & 1;
  const int m0 = blockIdx.y * 128;
  const int n0 = blockIdx.x * 128;
  const int K = nD;

  float4v acc[4][4] = {};
  for (int kt = 0; kt < K; kt += 32) {
    __syncthreads();
#pragma unroll
    for (int p = 0; p < 2; ++p) {
      int cch = p * 256 + wid * 64 + lane;
      int row = cch >> 2, cc = cch & 3;
      gload_lds16(A + (size_t)(m0 + row) * K + kt + cc * 8, As + (size_t)(p * 256 + wid * 64) * 8);
      gload_lds16(Bt + (size_t)(n0 + row) * K + kt + cc * 8, Bs + (size_t)(p * 256 + wid * 64) * 8);
    }
    __syncthreads();
    Frag16B a[4], b[4];
#pragma unroll
    for (int mi = 0; mi < 4; ++mi)
      a[mi].u4 = *(const uint4*)&As[(wm * 64 + mi * 16 + l16) * 32 + quad * 8];
#pragma unroll
    for (int ni = 0; ni < 4; ++ni)
      b[ni].u4 = *(const uint4*)&Bs[(wn * 64 + ni * 16 + l16) * 32 + quad * 8];
#pragma unroll
    for (int mi = 0; mi < 4; ++mi)
#pragma unroll
      for (int ni = 0; ni < 4; ++ni)
        acc[mi][ni] = __builtin_amdgcn_mfma_f32_16x16x32_bf16(a[mi].v, b[ni].v, acc[mi][ni], 0, 0, 0);
  }
#pragma unroll
  for (int mi = 0; mi < 4; ++mi)
#pragma unroll
    for (int ni = 0; ni < 4; ++ni)
#pragma unroll
      for (int r = 0; r < 4; ++r) {
        int row = m0 + wm * 64 + mi * 16 + quad * 4 + r;
        int col = n0 + wn * 64 + ni * 16 + l16;
        C[(size_t)row * nD + col] = acc[mi][ni][r];
      }
}

// ---------------------------------------------------------------- flash attention v2: paired causal tiles,
// double-buffered LDS staging w/ register prefetch, max-free exp2 softmax
static constexpr int KSTR = 68;
static constexpr float SC = 0.18033688011112042f;  // 0.125 * log2(e)

__global__ __launch_bounds__(256) void attn_kernel(const bf16* __restrict__ q_h,
                                                   const bf16* __restrict__ k_h,
                                                   const bf16* __restrict__ vt_h,
                                                   bf16* __restrict__ vals) {
  __shared__ bf16 Kl[2][64 * KSTR];
  __shared__ bf16 Vl[2][64 * KSTR];
  __shared__ bf16 Pl[4 * 16 * KSTR];

  const int t = threadIdx.x;
  const int lane = t & 63, wid = t >> 6, quad = lane >> 4, l16 = lane & 15;
  const int bh = blockIdx.y;
  const int b = bh >> 4, h = bh & 15;
  const int pairIdx = blockIdx.x;  // 0..15

  const bf16* Kbase = k_h + ((size_t)b * nS) * nD + h * 64;
  const bf16* Vbase = vt_h + (size_t)bh * 64 * nS;  // [d][s]
  bf16* Pw = Pl + wid * 16 * KSTR;

  const int row0 = t >> 3;         // 0..31
  const int c8 = (t & 7) * 8;

  for (int phase = 0; phase < 2; ++phase) {
    const int qt = phase == 0 ? (31 - pairIdx) : pairIdx;
    const int n = qt + 1;

    // Q fragments
    Frag16B qf[2];
    {
      int qrow = qt * 64 + wid * 16 + l16;
      const bf16* qp = q_h + ((size_t)(b * nS + qrow)) * nD + h * 64;
      qf[0].u4 = *(const uint4*)(qp + quad * 8);
      qf[1].u4 = *(const uint4*)(qp + 32 + quad * 8);
    }

    // prologue: load tile 0 into regs
    uint4 kreg[2], vreg[2];
#pragma unroll
    for (int i = 0; i < 2; ++i) {
      kreg[i] = *(const uint4*)(Kbase + (size_t)(row0 + i * 32) * nD + c8);
      vreg[i] = *(const uint4*)(Vbase + (size_t)(row0 + i * 32) * nS + c8);
    }

    lds_barrier();  // phase boundary: prior phase's LDS reads complete

    float4v o_acc[4] = {};
    float l_i[4] = {0.f, 0.f, 0.f, 0.f};

    for (int kt = 0; kt < n; ++kt) {
      bf16* Kb = Kl[kt & 1];
      bf16* Vb = Vl[kt & 1];
      // store staged regs -> LDS
#pragma unroll
      for (int i = 0; i < 2; ++i) {
        uint2 lo, hi;
        lo.x = kreg[i].x; lo.y = kreg[i].y; hi.x = kreg[i].z; hi.y = kreg[i].w;
        *(uint2*)&Kb[(row0 + i * 32) * KSTR + c8] = lo;
        *(uint2*)&Kb[(row0 + i * 32) * KSTR + c8 + 4] = hi;
        lo.x = vreg[i].x; lo.y = vreg[i].y; hi.x = vreg[i].z; hi.y = vreg[i].w;
        *(uint2*)&Vb[(row0 + i * 32) * KSTR + c8] = lo;
        *(uint2*)&Vb[(row0 + i * 32) * KSTR + c8 + 4] = hi;
      }
      // prefetch next tile (global loads stay in flight across the barrier)
      if (kt + 1 < n) {
#pragma unroll
        for (int i = 0; i < 2; ++i) {
          kreg[i] = *(const uint4*)(Kbase + (size_t)((kt + 1) * 64 + row0 + i * 32) * nD + c8);
          vreg[i] = *(const uint4*)(Vbase + (size_t)(row0 + i * 32) * nS + (kt + 1) * 64 + c8);
        }
      }
      lds_barrier();

      // QK^T
      float4v s_acc[4] = {};
#pragma unroll
      for (int ni = 0; ni < 4; ++ni) {
        Frag16B b0, b1;
        const bf16* kp = &Kb[(ni * 16 + l16) * KSTR + quad * 8];
        b0.u2[0] = *(const uint2*)(kp);
        b0.u2[1] = *(const uint2*)(kp + 4);
        b1.u2[0] = *(const uint2*)(kp + 32);
        b1.u2[1] = *(const uint2*)(kp + 36);
        s_acc[ni] = __builtin_amdgcn_mfma_f32_16x16x32_bf16(qf[0].v, b0.v, s_acc[ni], 0, 0, 0);
        s_acc[ni] = __builtin_amdgcn_mfma_f32_16x16x32_bf16(qf[1].v, b1.v, s_acc[ni], 0, 0, 0);
      }

      // max-free softmax: p = exp2(s * 0.125*log2e); masked -> 0
      const bool diag = (kt == qt);
      const int qr0 = qt * 64 + wid * 16 + quad * 4;
#pragma unroll
      for (int ni = 0; ni < 4; ++ni) {
        int key = kt * 64 + ni * 16 + l16;
#pragma unroll
        for (int r = 0; r < 4; ++r) {
          float x = s_acc[ni][r] * SC;
          if (diag && key > qr0 + r) x = -12000.0f;
          float p = fast_exp2(x);
          l_i[r] += p;
          Pw[(quad * 4 + r) * KSTR + ni * 16 + l16] = __float2bfloat16(p);
        }
      }
      asm volatile("s_waitcnt lgkmcnt(0)" ::: "memory");  // own P writes -> own reads

      // PV
      Frag16B pa[2];
      const bf16* pp = &Pw[l16 * KSTR];
      pa[0].u2[0] = *(const uint2*)(pp + quad * 8);
      pa[0].u2[1] = *(const uint2*)(pp + quad * 8 + 4);
      pa[1].u2[0] = *(const uint2*)(pp + 32 + quad * 8);
      pa[1].u2[1] = *(const uint2*)(pp + 32 + quad * 8 + 4);
#pragma unroll
      for (int ni = 0; ni < 4; ++ni) {
        Frag16B vb0, vb1;
        const bf16* vp = &Vb[(ni * 16 + l16) * KSTR + quad * 8];
        vb0.u2[0] = *(const uint2*)(vp);
        vb0.u2[1] = *(const uint2*)(vp + 4);
        vb1.u2[0] = *(const uint2*)(vp + 32);
        vb1.u2[1] = *(const uint2*)(vp + 36);
        o_acc[ni] = __builtin_amdgcn_mfma_f32_16x16x32_bf16(pa[0].v, vb0.v, o_acc[ni], 0, 0, 0);
        o_acc[ni] = __builtin_amdgcn_mfma_f32_16x16x32_bf16(pa[1].v, vb1.v, o_acc[ni], 0, 0, 0);
      }
    }

    // epilogue: deferred row-sum reduction, divide, store
#pragma unroll
    for (int r = 0; r < 4; ++r) {
#pragma unroll
      for (int m = 1; m <= 8; m <<= 1) l_i[r] += __shfl_xor(l_i[r], m, 64);
    }
    int qr0 = qt * 64 + wid * 16 + quad * 4;
#pragma unroll
    for (int ni = 0; ni < 4; ++ni)
#pragma unroll
      for (int r = 0; r < 4; ++r) {
        float o = o_acc[ni][r] / l_i[r];
        vals[((size_t)(b * nS + qr0 + r)) * nD + h * 64 + ni * 16 + l16] = __float2bfloat16(o);
      }
  }
}

// ---------------------------------------------------------------- launch
extern "C" void kernel_launch(void* const* d_in, const int* in_sizes, int n_in,
                              void* d_out, int out_size, void* d_ws, size_t ws_size,
                              hipStream_t stream) {
  const float* Qin = (const float*)d_in[0];
  const float* Kin = (const float*)d_in[1];
  const float* Vin = (const float*)d_in[2];
  const float* Wq = (const float*)d_in[4];
  const float* Wk = (const float*)d_in[5];
  const float* Wv = (const float*)d_in[6];
  const float* Wo = (const float*)d_in[7];
  float* out = (float*)d_out;

  char* ws = (char*)d_ws;
  const size_t MB = 1u << 20;
  bf16* Qbf = (bf16*)(ws + 0 * MB);
  bf16* Kbf = (bf16*)(ws + 8 * MB);
  bf16* Vbf = (bf16*)(ws + 16 * MB);
  bf16* WqT = (bf16*)(ws + 24 * MB);
  bf16* WkT = (bf16*)(ws + 26 * MB);
  bf16* WvT = (bf16*)(ws + 28 * MB);
  bf16* WoT = (bf16*)(ws + 30 * MB);
  bf16* cos_t = (bf16*)(ws + 32 * MB);
  bf16* sin_t = (bf16*)(ws + 33 * MB);
  bf16* q_h = (bf16*)(ws + 34 * MB);
  bf16* k_h = (bf16*)(ws + 42 * MB);
  bf16* vt_h = (bf16*)(ws + 50 * MB);
  bf16* vals = (bf16*)(ws + 58 * MB);

  prep_kernel<<<4160, 256, 0, stream>>>(Qin, Kin, Vin, Wq, Wk, Wv, Wo,
                                        Qbf, Kbf, Vbf, WqT, WkT, WvT, WoT, cos_t, sin_t);

  gemm_qkv_kernel<<<dim3(8, 32, 3), 256, 0, stream>>>(Qbf, Kbf, Vbf, WqT, WkT, WvT,
                                                      q_h, k_h, vt_h, cos_t, sin_t);

  attn_kernel<<<dim3(16, 32), 256, 0, stream>>>(q_h, k_h, vt_h, vals);

  gemm_out_kernel<<<dim3(8, 32), 256, 0, stream>>>(vals, WoT, out);
}